// Round 1
// 320.438 us; speedup vs baseline: 1.0811x; 1.0811x over previous
//
#include <hip/hip_runtime.h>
#include <cstdint>

#define BB 16
#define NN 25200
#define NCLS 80
#define ROW 85
#define MAXDET 300
#define HBINS 2048
#define CAP2 512
#define TGT 448
#define CONF_T 0.25f
#define IOU_T 0.45f
#define NT 1024

// unaligned-capable float4 (rows are only 4B-aligned: 340B stride)
typedef float f4u __attribute__((ext_vector_type(4), aligned(4)));

// ---------------- workspace layout (bytes) ----------------
// only scoreArr remains in global workspace; all other intermediates live in LDS
// scoreArr: f32 [BB][NN] at offset 0 (1,612,800 B)

// 4 lanes per row, float4-vectorized column scan.
// lane t reads float4 chunks jj = t, t+4, ..., (21 chunks cover cols 0..83),
// lane 1 additionally handles col 84. cols <5 skipped. Within-lane scan is
// ascending with strict >, quad reduce prefers lower col on ties ->
// first-occurrence argmax, bitwise identical to reference.
__global__ __launch_bounds__(256) void k_pre(const float* __restrict__ pred,
                                             float* __restrict__ scoreArr) {
    int tid = threadIdx.x;
    int t = tid & 3;
    int row = blockIdx.x * 64 + (tid >> 2);
    const float* rp = pred + (size_t)row * ROW;
    float obj = rp[4];                          // quad-broadcast load (L1 hit)
    float best = -1.0f; int bc = 1 << 20;
#pragma unroll
    for (int i = 0; i < 6; ++i) {
        int jj = t + 4 * i;
        if (jj < 21) {
            f4u v4 = *reinterpret_cast<const f4u*>(rp + 4 * jj);
            int c0 = 4 * jj;
#pragma unroll
            for (int e = 0; e < 4; ++e) {
                int col = c0 + e;
                if (col >= 5) {
                    float v = __fmul_rn(v4[e], obj);
                    if (v > best) { best = v; bc = col; }
                }
            }
        }
    }
    if (t == 1) {                               // tail col 84 (class 79)
        float v = __fmul_rn(rp[84], obj);
        if (v > best) { best = v; bc = 84; }
    }
#pragma unroll
    for (int d = 1; d <= 2; d <<= 1) {
        float ob = __shfl_xor(best, d);
        int   oc = __shfl_xor(bc, d);
        if (ob > best || (ob == best && oc < bc)) { best = ob; bc = oc; }
    }
    if (t == 0) {
        bool valid = (obj > CONF_T) && (best > CONF_T);
        scoreArr[row] = valid ? best : -1.0f;
    }
}

// Fused select + mask + finalize: 16 blocks x 1024 threads, one block per image.
// All intermediates (candidates, suppression masks) stay in LDS.
// hist/csum (phases 1-2) overlap the 32KB mask array (later phases) via union.
__global__ __launch_bounds__(NT) void k_fused(const float* __restrict__ pred,
                                              const float* __restrict__ scoreArr,
                                              const float* __restrict__ logits,
                                              float* __restrict__ out) {
    __shared__ union {
        struct { unsigned hist[HBINS]; unsigned csum[257]; } h;
        unsigned long long maskS[CAP2][8];
    } u;
    __shared__ unsigned long long keys[CAP2];
    __shared__ float4 cbox_s[CAP2];
    __shared__ float4 raw_s[CAP2];
    __shared__ unsigned ccls_s[CAP2];
    __shared__ unsigned long long maskT_s[8][64];
    __shared__ unsigned long long keepm_s[8];
    __shared__ unsigned kidx[64];
    __shared__ unsigned rowsrc_s[MAXDET];
    __shared__ int flags[2];  // 0=cnt 1=thr
    __shared__ int s_kept;

    int b = blockIdx.x, tid = threadIdx.x;
    int lane = tid & 63;

    for (int k = tid; k < HBINS; k += NT) u.h.hist[k] = 0u;
    if (tid == 0) { flags[0] = 0; flags[1] = 0; }
    __syncthreads();

    // phase 1: register-cache scores + LDS histogram
    float sreg[25];
#pragma unroll
    for (int t = 0; t < 25; ++t) {
        int n = tid + t * NT;
        float s = (n < NN) ? scoreArr[(size_t)b * NN + n] : -1.0f;
        sreg[t] = s;
        if (s > 0.0f) {
            unsigned key = (__float_as_uint(s) - 0x3E800000u) >> 13;
            if (key > HBINS - 1) key = HBINS - 1;
            atomicAdd(&u.h.hist[key], 1u);
        }
    }
    __syncthreads();

    // phase 2: suffix scan -> threshold bin (verified logic, verbatim)
    if (tid < 256) {
        unsigned cs = 0;
#pragma unroll
        for (int t = 0; t < 8; ++t) cs += u.h.hist[tid * 8 + t];
        u.h.csum[tid] = cs;
    }
    __syncthreads();
    for (int off = 1; off < 256; off <<= 1) {
        unsigned v = 0, add = 0;
        if (tid < 256) {
            v = u.h.csum[tid];
            add = (tid + off < 256) ? u.h.csum[tid + off] : 0u;
        }
        __syncthreads();
        if (tid < 256) u.h.csum[tid] = v + add;
        __syncthreads();
    }
    if (tid < 256) {
        unsigned Sc = u.h.csum[tid];
        unsigned Sn = (tid < 255) ? u.h.csum[tid + 1] : 0u;
        if (Sc >= TGT && (tid == 255 || Sn < TGT)) {
            unsigned cum = Sn;
            int t = tid * 8;
            for (int k = tid * 8 + 7; k >= tid * 8; --k) {
                cum += u.h.hist[k];
                if (cum >= TGT) { t = k; break; }
            }
            flags[1] = t;
        }
    }
    __syncthreads();
    unsigned thr = (unsigned)flags[1];

    // phase 3: wave-aggregated compaction (1 atomic per wave per round)
#pragma unroll
    for (int t = 0; t < 25; ++t) {
        int n = tid + t * NT;
        float s = sreg[t];
        bool win = false;
        if (s > 0.0f) {
            unsigned key = (__float_as_uint(s) - 0x3E800000u) >> 13;
            if (key > HBINS - 1) key = HBINS - 1;
            win = (key >= thr);
        }
        unsigned long long m = __ballot(win);
        if (m) {
            int lead = __ffsll((long long)m) - 1;
            int base = 0;
            if (lane == lead) base = atomicAdd(&flags[0], __popcll(m));
            base = __shfl(base, lead);
            if (win) {
                int pos = base + __popcll(m & ((1ULL << lane) - 1ULL));
                if (pos < CAP2)
                    keys[pos] = ((unsigned long long)__float_as_uint(s) << 32)
                              | (unsigned long long)(0xFFFFFFFFu - (unsigned)n);
            }
        }
    }
    __syncthreads();
    int c = min(flags[0], CAP2);
    for (int p = tid; p < CAP2; p += NT)
        if (p >= c) keys[p] = 0ULL;
    __syncthreads();

    // phase 4: bitonic sort 512 u64 desc == (score desc, idx asc)
    for (int k = 2; k <= CAP2; k <<= 1) {
        for (int j = k >> 1; j > 0; j >>= 1) {
            for (int i = tid; i < CAP2; i += NT) {
                int ixj = i ^ j;
                if (ixj > i) {
                    unsigned long long k1 = keys[i], k2 = keys[ixj];
                    bool sw = ((i & k) == 0) ? (k1 < k2) : (k1 > k2);
                    if (sw) { keys[i] = k2; keys[ixj] = k1; }
                }
            }
            __syncthreads();
        }
    }

    // phase 5: recompute argmax/box for sorted candidates (bitwise = reference)
    if (tid < CAP2) {
        int p = tid;
        if (p < c) {
            int n = (int)(0xFFFFFFFFu - (unsigned)keys[p]);
            const float* rp = pred + ((size_t)b * NN + n) * ROW;
            float cx = rp[0], cy = rp[1], w = rp[2], h = rp[3], obj = rp[4];
            float best = __fmul_rn(rp[5], obj);
            int bj = 0;
#pragma unroll 8
            for (int cc = 1; cc < NCLS; ++cc) {
                float v = __fmul_rn(rp[5 + cc], obj);
                if (v > best) { best = v; bj = cc; }
            }
            float hw = __fmul_rn(w, 0.5f), hh = __fmul_rn(h, 0.5f);
            float4 bb = make_float4(__fsub_rn(cx, hw), __fsub_rn(cy, hh),
                                    __fadd_rn(cx, hw), __fadd_rn(cy, hh));
            raw_s[p] = bb;
            float off = __fmul_rn((float)bj, 4096.0f);
            cbox_s[p] = make_float4(__fadd_rn(bb.x, off), __fadd_rn(bb.y, off),
                                    __fadd_rn(bb.z, off), __fadd_rn(bb.w, off));
            ccls_s[p] = (unsigned)bj;
        } else {
            raw_s[p]  = make_float4(0.f, 0.f, 0.f, 0.f);
            cbox_s[p] = make_float4(0.f, 0.f, 0.f, 0.f);
            ccls_s[p] = 0u;
        }
    }
    __syncthreads();

    // mask phase: word-w suppression bits for all rows (row-major), in LDS.
    // 4096 (i,w) words over 1024 threads; w is wave-uniform -> cb[j] broadcast.
    for (int k = tid; k < CAP2 * 8; k += NT) {
        int i = k & (CAP2 - 1);
        int w = k >> 9;
        int jbase = w << 6;
        unsigned long long m = 0ULL;
        if (i < c && i < jbase + 63) {
            float4 ci = cbox_s[i];
            float a1 = __fmul_rn(__fsub_rn(ci.z, ci.x), __fsub_rn(ci.w, ci.y));
#pragma unroll 4
            for (int jj = 0; jj < 64; ++jj) {
                int j = jbase + jj;
                float4 cj = cbox_s[j];
                float ltx = fmaxf(ci.x, cj.x), lty = fmaxf(ci.y, cj.y);
                float rbx = fminf(ci.z, cj.z), rby = fminf(ci.w, cj.w);
                float ww = fmaxf(__fsub_rn(rbx, ltx), 0.0f);
                float hh = fmaxf(__fsub_rn(rby, lty), 0.0f);
                float inter = __fmul_rn(ww, hh);
                if (j > i && inter > 0.0f) {
                    float a2 = __fmul_rn(__fsub_rn(cj.z, cj.x), __fsub_rn(cj.w, cj.y));
                    float denom = __fadd_rn(__fsub_rn(__fadd_rn(a1, a2), inter), 1e-9f);
                    if (inter / denom > IOU_T) m |= (1ULL << jj);
                }
            }
        }
        u.maskS[i][w] = m;
    }
    // transposed diagonal: column l holds bits of earlier same-word suppressors.
    if (tid < 512) {
        int w = tid >> 6, l = tid & 63;
        int jbase = w << 6, p = jbase + l;
        unsigned long long m = 0ULL;
        if (p < c) {
            float4 cl = cbox_s[p];
            float a2 = __fmul_rn(__fsub_rn(cl.z, cl.x), __fsub_rn(cl.w, cl.y));
            for (int ii = 0; ii < 64; ++ii) {
                float4 ci = cbox_s[jbase + ii];
                float ltx = fmaxf(ci.x, cl.x), lty = fmaxf(ci.y, cl.y);
                float rbx = fminf(ci.z, cl.z), rby = fminf(ci.w, cl.w);
                float ww = fmaxf(__fsub_rn(rbx, ltx), 0.0f);
                float hh = fmaxf(__fsub_rn(rby, lty), 0.0f);
                float inter = __fmul_rn(ww, hh);
                if (ii < l && inter > 0.0f) {
                    float a1 = __fmul_rn(__fsub_rn(ci.z, ci.x), __fsub_rn(ci.w, ci.y));
                    float denom = __fadd_rn(__fsub_rn(__fadd_rn(a1, a2), inter), 1e-9f);
                    if (inter / denom > IOU_T) m |= (1ULL << ii);
                }
            }
        }
        maskT_s[w][l] = m;
    }
    __syncthreads();

    // fin phase: ballot-fixpoint greedy resolve (exact) + outputs.
    if (tid < 64) {
        unsigned long long remq = 0ULL;  // lane q<8 owns rem word q
        int kept = 0;
        for (int w = 0; w < 8; ++w) {
            int base = w << 6;
            unsigned long long tw = __shfl(remq, w);
            bool pre = ((tw >> lane) & 1ULL) != 0ULL;
            bool validl = (base + lane) < c;
            unsigned long long Cl = maskT_s[w][lane];
            unsigned long long initK = __ballot(validl && !pre);
            unsigned long long K = initK;
            // fixpoint: odd/even iterates sandwich the greedy set; exact on converge
            for (int it = 0; it < 64; ++it) {
                bool sup = (Cl & K & ((1ULL << lane) - 1ULL)) != 0ULL;
                unsigned long long K2 = initK & __ballot(!sup);
                if (K2 == K) break;
                K = K2;
            }
            // truncate to MAXDET total (reference scans exactly 300 picks)
            int limit = MAXDET - kept;
            int nk = __popcll(K);
            if (nk > limit) {
                if (limit <= 0) K = 0ULL;
                else {
                    int pref = __popcll(K & ((2ULL << lane) - 1ULL));  // bits 0..lane
                    bool el = ((K >> lane) & 1ULL) && (pref <= limit);
                    K = __ballot(el);
                }
            }
            kept += __popcll(K);
            if (lane == 0) keepm_s[w] = K;
            // cross-word rem update: 64 lanes fetch kept rows' words in parallel
            if (K != 0ULL && w < 7) {
                if ((K >> lane) & 1ULL) {
                    int r = __popcll(K & ((1ULL << lane) - 1ULL));
                    kidx[r] = (unsigned)lane;
                }
                __builtin_amdgcn_s_waitcnt(0);
                int nkk = __popcll(K);
                int q = lane & 7, slot = lane >> 3;
                unsigned long long acc = 0ULL;
                for (int t = slot; t < nkk; t += 8)
                    acc |= u.maskS[base + (int)kidx[t]][q];
                acc |= __shfl_xor(acc, 8);
                acc |= __shfl_xor(acc, 16);
                acc |= __shfl_xor(acc, 32);
                if (slot == 0) remq |= acc;
            }
        }
        if (lane == 0) s_kept = kept;
    }
    __syncthreads();
    int kept = s_kept;

    float* dets = out;
    float* lg   = out + (size_t)BB * MAXDET * 6;
    float* kpo  = lg  + (size_t)BB * MAXDET * NCLS;

    // rank-scatter kept rows directly to dets; record source indices
    for (int p = tid; p < CAP2; p += NT) {
        if (p < c) {
            int w = p >> 6, bitp = p & 63;
            unsigned long long kw = keepm_s[w];
            if ((kw >> bitp) & 1ULL) {
                int rank = __popcll(kw & ((1ULL << bitp) - 1ULL));
                for (int q = 0; q < w; ++q) rank += __popcll(keepm_s[q]);
                if (rank < MAXDET) {
                    float4 bb = raw_s[p];
                    unsigned long long key = keys[p];
                    float* dr = dets + ((size_t)b * MAXDET + rank) * 6;
                    dr[0] = bb.x; dr[1] = bb.y; dr[2] = bb.z; dr[3] = bb.w;
                    dr[4] = __uint_as_float((unsigned)(key >> 32));
                    dr[5] = (float)ccls_s[p];
                    rowsrc_s[rank] = 0xFFFFFFFFu - (unsigned)key;
                }
            }
        }
    }
    for (int i = tid; i < MAXDET; i += NT) {
        if (i >= kept) {
            float* dr = dets + ((size_t)b * MAXDET + i) * 6;
#pragma unroll
            for (int q = 0; q < 6; ++q) dr[q] = 0.0f;
        }
        kpo[b * MAXDET + i] = (i < kept) ? 1.0f : 0.0f;
    }
    __syncthreads();
    for (int i = tid; i < MAXDET * NCLS; i += NT) {
        int t = i / NCLS, col = i - t * NCLS;
        float v = 0.0f;
        if (t < kept) v = logits[((size_t)b * NN + rowsrc_s[t]) * NCLS + col];
        lg[(size_t)b * MAXDET * NCLS + i] = v;
    }
}

extern "C" void kernel_launch(void* const* d_in, const int* in_sizes, int n_in,
                              void* d_out, int out_size, void* d_ws, size_t ws_size,
                              hipStream_t stream) {
    const float* pred   = (const float*)d_in[0];
    const float* logits = (const float*)d_in[1];
    float* out = (float*)d_out;
    float* scr = (float*)d_ws;

    k_pre<<<6300, 256, 0, stream>>>(pred, scr);                 // 403200/64 exact
    k_fused<<<BB, NT, 0, stream>>>(pred, scr, logits, out);
}

// Round 2
// 304.951 us; speedup vs baseline: 1.1360x; 1.0508x over previous
//
#include <hip/hip_runtime.h>
#include <cstdint>

#define BB 16
#define NN 25200
#define NCLS 80
#define ROW 85
#define MAXDET 300
#define HBINS 2048
#define CAP2 512
#define TGT 448
#define CONF_T 0.25f
#define IOU_T 0.45f
#define NT 1024

// unaligned-capable float4 (rows are only 4B-aligned: 340B stride)
typedef float f4u __attribute__((ext_vector_type(4), aligned(4)));

// ---------------- workspace layout (bytes) ----------------
// scoreArr: f32 [BB][NN] at offset 0                      (1,612,800 B)
// recG:     f4  [BB][NN][2] at OFF_REC: {box.xyxy},{clsbits,0,0,0} (12,902,400 B)
static const size_t OFF_REC = 1612800;

// 4 lanes per row, float4-vectorized column scan.
// lane t reads float4 chunks jj = t, t+4, ..., (21 chunks cover cols 0..83),
// lane 1 additionally handles col 84. cols <5 skipped. Within-lane scan is
// ascending with strict >, quad reduce prefers lower col on ties ->
// first-occurrence argmax, bitwise identical to reference.
// Lane t=0 (which holds cols 0..3 from chunk 0) also emits the xyxy box and
// argmax class as a 32B record so the fused kernel never touches pred again.
__global__ __launch_bounds__(256) void k_pre(const float* __restrict__ pred,
                                             float* __restrict__ scoreArr,
                                             float4* __restrict__ recG) {
    int tid = threadIdx.x;
    int t = tid & 3;
    int row = blockIdx.x * 64 + (tid >> 2);
    const float* rp = pred + (size_t)row * ROW;
    float obj = rp[4];                          // quad-broadcast load (L1 hit)
    float best = -1.0f; int bc = 1 << 20;
    f4u c0v;
#pragma unroll
    for (int i = 0; i < 6; ++i) {
        int jj = t + 4 * i;
        if (jj < 21) {
            f4u v4 = *reinterpret_cast<const f4u*>(rp + 4 * jj);
            if (jj == 0) c0v = v4;              // only t==0, i==0
            int c0 = 4 * jj;
#pragma unroll
            for (int e = 0; e < 4; ++e) {
                int col = c0 + e;
                if (col >= 5) {
                    float v = __fmul_rn(v4[e], obj);
                    if (v > best) { best = v; bc = col; }
                }
            }
        }
    }
    if (t == 1) {                               // tail col 84 (class 79)
        float v = __fmul_rn(rp[84], obj);
        if (v > best) { best = v; bc = 84; }
    }
#pragma unroll
    for (int d = 1; d <= 2; d <<= 1) {
        float ob = __shfl_xor(best, d);
        int   oc = __shfl_xor(bc, d);
        if (ob > best || (ob == best && oc < bc)) { best = ob; bc = oc; }
    }
    if (t == 0) {
        bool valid = (obj > CONF_T) && (best > CONF_T);
        scoreArr[row] = valid ? best : -1.0f;
        // box + class record (ops bitwise-identical to the old phase-5 path)
        float cx = c0v[0], cy = c0v[1], w = c0v[2], h = c0v[3];
        float hw = __fmul_rn(w, 0.5f), hh = __fmul_rn(h, 0.5f);
        float4 bb = make_float4(__fsub_rn(cx, hw), __fsub_rn(cy, hh),
                                __fadd_rn(cx, hw), __fadd_rn(cy, hh));
        int bj = bc - 5;
        recG[(size_t)row * 2]     = bb;
        recG[(size_t)row * 2 + 1] = make_float4(__uint_as_float((unsigned)bj), 0.f, 0.f, 0.f);
    }
}

// Fused select + mask + finalize: 16 blocks x 1024 threads, one block per image.
// All intermediates (candidates, suppression masks) stay in LDS.
// hist/csum (phases 1-2) overlap the 32KB mask array (later phases) via union.
__global__ __launch_bounds__(NT) void k_fused(const float4* __restrict__ recG,
                                              const float* __restrict__ scoreArr,
                                              const float* __restrict__ logits,
                                              float* __restrict__ out) {
    __shared__ union {
        struct { unsigned hist[HBINS]; unsigned csum[257]; } h;
        unsigned long long maskS[CAP2][8];
    } u;
    __shared__ unsigned long long keys[CAP2];
    __shared__ float4 cbox_s[CAP2];
    __shared__ float4 raw_s[CAP2];
    __shared__ unsigned ccls_s[CAP2];
    __shared__ unsigned long long maskT_s[8][64];
    __shared__ unsigned long long keepm_s[8];
    __shared__ unsigned kidx[64];
    __shared__ unsigned rowsrc_s[MAXDET];
    __shared__ int flags[2];  // 0=cnt 1=thr
    __shared__ int s_kept;

    int b = blockIdx.x, tid = threadIdx.x;
    int lane = tid & 63;

    for (int k = tid; k < HBINS; k += NT) u.h.hist[k] = 0u;
    if (tid == 0) { flags[0] = 0; flags[1] = 0; }
    __syncthreads();

    // phase 1: register-cache scores + LDS histogram
    float sreg[25];
#pragma unroll
    for (int t = 0; t < 25; ++t) {
        int n = tid + t * NT;
        float s = (n < NN) ? scoreArr[(size_t)b * NN + n] : -1.0f;
        sreg[t] = s;
        if (s > 0.0f) {
            unsigned key = (__float_as_uint(s) - 0x3E800000u) >> 13;
            if (key > HBINS - 1) key = HBINS - 1;
            atomicAdd(&u.h.hist[key], 1u);
        }
    }
    __syncthreads();

    // phase 2: suffix scan -> threshold bin (verified logic, verbatim)
    if (tid < 256) {
        unsigned cs = 0;
#pragma unroll
        for (int t = 0; t < 8; ++t) cs += u.h.hist[tid * 8 + t];
        u.h.csum[tid] = cs;
    }
    __syncthreads();
    for (int off = 1; off < 256; off <<= 1) {
        unsigned v = 0, add = 0;
        if (tid < 256) {
            v = u.h.csum[tid];
            add = (tid + off < 256) ? u.h.csum[tid + off] : 0u;
        }
        __syncthreads();
        if (tid < 256) u.h.csum[tid] = v + add;
        __syncthreads();
    }
    if (tid < 256) {
        unsigned Sc = u.h.csum[tid];
        unsigned Sn = (tid < 255) ? u.h.csum[tid + 1] : 0u;
        if (Sc >= TGT && (tid == 255 || Sn < TGT)) {
            unsigned cum = Sn;
            int t = tid * 8;
            for (int k = tid * 8 + 7; k >= tid * 8; --k) {
                cum += u.h.hist[k];
                if (cum >= TGT) { t = k; break; }
            }
            flags[1] = t;
        }
    }
    __syncthreads();
    unsigned thr = (unsigned)flags[1];

    // phase 3: wave-aggregated compaction (1 atomic per wave per round)
#pragma unroll
    for (int t = 0; t < 25; ++t) {
        int n = tid + t * NT;
        float s = sreg[t];
        bool win = false;
        if (s > 0.0f) {
            unsigned key = (__float_as_uint(s) - 0x3E800000u) >> 13;
            if (key > HBINS - 1) key = HBINS - 1;
            win = (key >= thr);
        }
        unsigned long long m = __ballot(win);
        if (m) {
            int lead = __ffsll((long long)m) - 1;
            int base = 0;
            if (lane == lead) base = atomicAdd(&flags[0], __popcll(m));
            base = __shfl(base, lead);
            if (win) {
                int pos = base + __popcll(m & ((1ULL << lane) - 1ULL));
                if (pos < CAP2)
                    keys[pos] = ((unsigned long long)__float_as_uint(s) << 32)
                              | (unsigned long long)(0xFFFFFFFFu - (unsigned)n);
            }
        }
    }
    __syncthreads();
    int c = min(flags[0], CAP2);
    for (int p = tid; p < CAP2; p += NT)
        if (p >= c) keys[p] = 0ULL;
    __syncthreads();

    // phase 4: bitonic sort 512 u64 desc == (score desc, idx asc)
    for (int k = 2; k <= CAP2; k <<= 1) {
        for (int j = k >> 1; j > 0; j >>= 1) {
            for (int i = tid; i < CAP2; i += NT) {
                int ixj = i ^ j;
                if (ixj > i) {
                    unsigned long long k1 = keys[i], k2 = keys[ixj];
                    bool sw = ((i & k) == 0) ? (k1 < k2) : (k1 > k2);
                    if (sw) { keys[i] = k2; keys[ixj] = k1; }
                }
            }
            __syncthreads();
        }
    }

    // phase 5: fetch precomputed record per sorted candidate (2 x dwordx4,
    // single 128B line) — replaces the 85-scalar-load row recompute.
    if (tid < CAP2) {
        int p = tid;
        if (p < c) {
            int n = (int)(0xFFFFFFFFu - (unsigned)keys[p]);
            size_t rb = ((size_t)b * NN + n) * 2;
            float4 bb = recG[rb];
            unsigned bj = __float_as_uint(recG[rb + 1].x);
            raw_s[p] = bb;
            float off = __fmul_rn((float)bj, 4096.0f);
            cbox_s[p] = make_float4(__fadd_rn(bb.x, off), __fadd_rn(bb.y, off),
                                    __fadd_rn(bb.z, off), __fadd_rn(bb.w, off));
            ccls_s[p] = bj;
        } else {
            raw_s[p]  = make_float4(0.f, 0.f, 0.f, 0.f);
            cbox_s[p] = make_float4(0.f, 0.f, 0.f, 0.f);
            ccls_s[p] = 0u;
        }
    }
    __syncthreads();

    // mask phase: word-w suppression bits for all rows (row-major), in LDS.
    // 4096 (i,w) words over 1024 threads; w is wave-uniform -> cb[j] broadcast.
    for (int k = tid; k < CAP2 * 8; k += NT) {
        int i = k & (CAP2 - 1);
        int w = k >> 9;
        int jbase = w << 6;
        unsigned long long m = 0ULL;
        if (i < c && i < jbase + 63) {
            float4 ci = cbox_s[i];
            float a1 = __fmul_rn(__fsub_rn(ci.z, ci.x), __fsub_rn(ci.w, ci.y));
#pragma unroll 4
            for (int jj = 0; jj < 64; ++jj) {
                int j = jbase + jj;
                float4 cj = cbox_s[j];
                float ltx = fmaxf(ci.x, cj.x), lty = fmaxf(ci.y, cj.y);
                float rbx = fminf(ci.z, cj.z), rby = fminf(ci.w, cj.w);
                float ww = fmaxf(__fsub_rn(rbx, ltx), 0.0f);
                float hh = fmaxf(__fsub_rn(rby, lty), 0.0f);
                float inter = __fmul_rn(ww, hh);
                if (j > i && inter > 0.0f) {
                    float a2 = __fmul_rn(__fsub_rn(cj.z, cj.x), __fsub_rn(cj.w, cj.y));
                    float denom = __fadd_rn(__fsub_rn(__fadd_rn(a1, a2), inter), 1e-9f);
                    if (inter / denom > IOU_T) m |= (1ULL << jj);
                }
            }
        }
        u.maskS[i][w] = m;
    }
    // transposed diagonal: column l holds bits of earlier same-word suppressors.
    if (tid < 512) {
        int w = tid >> 6, l = tid & 63;
        int jbase = w << 6, p = jbase + l;
        unsigned long long m = 0ULL;
        if (p < c) {
            float4 cl = cbox_s[p];
            float a2 = __fmul_rn(__fsub_rn(cl.z, cl.x), __fsub_rn(cl.w, cl.y));
            for (int ii = 0; ii < 64; ++ii) {
                float4 ci = cbox_s[jbase + ii];
                float ltx = fmaxf(ci.x, cl.x), lty = fmaxf(ci.y, cl.y);
                float rbx = fminf(ci.z, cl.z), rby = fminf(ci.w, cl.w);
                float ww = fmaxf(__fsub_rn(rbx, ltx), 0.0f);
                float hh = fmaxf(__fsub_rn(rby, lty), 0.0f);
                float inter = __fmul_rn(ww, hh);
                if (ii < l && inter > 0.0f) {
                    float a1 = __fmul_rn(__fsub_rn(ci.z, ci.x), __fsub_rn(ci.w, ci.y));
                    float denom = __fadd_rn(__fsub_rn(__fadd_rn(a1, a2), inter), 1e-9f);
                    if (inter / denom > IOU_T) m |= (1ULL << ii);
                }
            }
        }
        maskT_s[w][l] = m;
    }
    __syncthreads();

    // fin phase: ballot-fixpoint greedy resolve (exact) + outputs.
    if (tid < 64) {
        unsigned long long remq = 0ULL;  // lane q<8 owns rem word q
        int kept = 0;
        for (int w = 0; w < 8; ++w) {
            int base = w << 6;
            unsigned long long tw = __shfl(remq, w);
            bool pre = ((tw >> lane) & 1ULL) != 0ULL;
            bool validl = (base + lane) < c;
            unsigned long long Cl = maskT_s[w][lane];
            unsigned long long initK = __ballot(validl && !pre);
            unsigned long long K = initK;
            // fixpoint: odd/even iterates sandwich the greedy set; exact on converge
            for (int it = 0; it < 64; ++it) {
                bool sup = (Cl & K & ((1ULL << lane) - 1ULL)) != 0ULL;
                unsigned long long K2 = initK & __ballot(!sup);
                if (K2 == K) break;
                K = K2;
            }
            // truncate to MAXDET total (reference scans exactly 300 picks)
            int limit = MAXDET - kept;
            int nk = __popcll(K);
            if (nk > limit) {
                if (limit <= 0) K = 0ULL;
                else {
                    int pref = __popcll(K & ((2ULL << lane) - 1ULL));  // bits 0..lane
                    bool el = ((K >> lane) & 1ULL) && (pref <= limit);
                    K = __ballot(el);
                }
            }
            kept += __popcll(K);
            if (lane == 0) keepm_s[w] = K;
            // cross-word rem update: 64 lanes fetch kept rows' words in parallel
            if (K != 0ULL && w < 7) {
                if ((K >> lane) & 1ULL) {
                    int r = __popcll(K & ((1ULL << lane) - 1ULL));
                    kidx[r] = (unsigned)lane;
                }
                __builtin_amdgcn_s_waitcnt(0);
                int nkk = __popcll(K);
                int q = lane & 7, slot = lane >> 3;
                unsigned long long acc = 0ULL;
                for (int t = slot; t < nkk; t += 8)
                    acc |= u.maskS[base + (int)kidx[t]][q];
                acc |= __shfl_xor(acc, 8);
                acc |= __shfl_xor(acc, 16);
                acc |= __shfl_xor(acc, 32);
                if (slot == 0) remq |= acc;
            }
        }
        if (lane == 0) s_kept = kept;
    }
    __syncthreads();
    int kept = s_kept;

    float* dets = out;
    float* lg   = out + (size_t)BB * MAXDET * 6;
    float* kpo  = lg  + (size_t)BB * MAXDET * NCLS;

    // rank-scatter kept rows directly to dets; record source indices
    for (int p = tid; p < CAP2; p += NT) {
        if (p < c) {
            int w = p >> 6, bitp = p & 63;
            unsigned long long kw = keepm_s[w];
            if ((kw >> bitp) & 1ULL) {
                int rank = __popcll(kw & ((1ULL << bitp) - 1ULL));
                for (int q = 0; q < w; ++q) rank += __popcll(keepm_s[q]);
                if (rank < MAXDET) {
                    float4 bb = raw_s[p];
                    unsigned long long key = keys[p];
                    float* dr = dets + ((size_t)b * MAXDET + rank) * 6;
                    dr[0] = bb.x; dr[1] = bb.y; dr[2] = bb.z; dr[3] = bb.w;
                    dr[4] = __uint_as_float((unsigned)(key >> 32));
                    dr[5] = (float)ccls_s[p];
                    rowsrc_s[rank] = 0xFFFFFFFFu - (unsigned)key;
                }
            }
        }
    }
    for (int i = tid; i < MAXDET; i += NT) {
        if (i >= kept) {
            float* dr = dets + ((size_t)b * MAXDET + i) * 6;
#pragma unroll
            for (int q = 0; q < 6; ++q) dr[q] = 0.0f;
        }
        kpo[b * MAXDET + i] = (i < kept) ? 1.0f : 0.0f;
    }
    __syncthreads();
    // logits gather, float2-vectorized (NCLS=80 even; bases 8B-aligned)
    {
        const int HC = NCLS / 2;  // 40
        for (int i2 = tid; i2 < MAXDET * HC; i2 += NT) {
            int t = i2 / HC, col2 = i2 - t * HC;
            float2 v = make_float2(0.f, 0.f);
            if (t < kept)
                v = *reinterpret_cast<const float2*>(
                        logits + ((size_t)b * NN + rowsrc_s[t]) * NCLS + col2 * 2);
            *reinterpret_cast<float2*>(
                lg + (size_t)b * MAXDET * NCLS + (size_t)t * NCLS + col2 * 2) = v;
        }
    }
}

extern "C" void kernel_launch(void* const* d_in, const int* in_sizes, int n_in,
                              void* d_out, int out_size, void* d_ws, size_t ws_size,
                              hipStream_t stream) {
    const float* pred   = (const float*)d_in[0];
    const float* logits = (const float*)d_in[1];
    float* out = (float*)d_out;
    char* ws = (char*)d_ws;

    float* scr   = (float*)ws;
    float4* recG = (float4*)(ws + OFF_REC);

    k_pre<<<6300, 256, 0, stream>>>(pred, scr, recG);           // 403200/64 exact
    k_fused<<<BB, NT, 0, stream>>>(recG, scr, logits, out);
}

// Round 3
// 290.804 us; speedup vs baseline: 1.1913x; 1.0486x over previous
//
#include <hip/hip_runtime.h>
#include <cstdint>

#define BB 16
#define NN 25200
#define NCLS 80
#define ROW 85
#define MAXDET 300
#define HBINS 2048
#define CAP2 512
#define TGT 448
#define CONF_T 0.25f
#define IOU_T 0.45f
#define NT 1024

// unaligned-capable float4 (rows are only 4B-aligned: 340B stride)
typedef float f4u __attribute__((ext_vector_type(4), aligned(4)));

// ---------------- workspace layout (bytes) ----------------
// scoreArr: f32 [BB][NN] at offset 0                      (1,612,800 B)
// recG:     f4  [BB][NN][2] at OFF_REC: {box.xyxy},{clsbits,0,0,0} (12,902,400 B)
static const size_t OFF_REC = 1612800;

// 4 lanes per row, float4-vectorized column scan.
// lane t reads float4 chunks jj = t, t+4, ..., (21 chunks cover cols 0..83),
// lane 1 additionally handles col 84. cols <5 skipped. Within-lane scan is
// ascending with strict >, quad reduce prefers lower col on ties ->
// first-occurrence argmax, bitwise identical to reference.
// Lane t=0 (which holds cols 0..3 from chunk 0) also emits the xyxy box and
// argmax class as a 32B record so the fused kernel never touches pred again.
__global__ __launch_bounds__(256) void k_pre(const float* __restrict__ pred,
                                             float* __restrict__ scoreArr,
                                             float4* __restrict__ recG) {
    int tid = threadIdx.x;
    int t = tid & 3;
    int row = blockIdx.x * 64 + (tid >> 2);
    const float* rp = pred + (size_t)row * ROW;
    float obj = rp[4];                          // quad-broadcast load (L1 hit)
    float best = -1.0f; int bc = 1 << 20;
    f4u c0v;
#pragma unroll
    for (int i = 0; i < 6; ++i) {
        int jj = t + 4 * i;
        if (jj < 21) {
            f4u v4 = *reinterpret_cast<const f4u*>(rp + 4 * jj);
            if (jj == 0) c0v = v4;              // only t==0, i==0
            int c0 = 4 * jj;
#pragma unroll
            for (int e = 0; e < 4; ++e) {
                int col = c0 + e;
                if (col >= 5) {
                    float v = __fmul_rn(v4[e], obj);
                    if (v > best) { best = v; bc = col; }
                }
            }
        }
    }
    if (t == 1) {                               // tail col 84 (class 79)
        float v = __fmul_rn(rp[84], obj);
        if (v > best) { best = v; bc = 84; }
    }
#pragma unroll
    for (int d = 1; d <= 2; d <<= 1) {
        float ob = __shfl_xor(best, d);
        int   oc = __shfl_xor(bc, d);
        if (ob > best || (ob == best && oc < bc)) { best = ob; bc = oc; }
    }
    if (t == 0) {
        bool valid = (obj > CONF_T) && (best > CONF_T);
        scoreArr[row] = valid ? best : -1.0f;
        // box + class record (ops bitwise-identical to the old phase-5 path)
        float cx = c0v[0], cy = c0v[1], w = c0v[2], h = c0v[3];
        float hw = __fmul_rn(w, 0.5f), hh = __fmul_rn(h, 0.5f);
        float4 bb = make_float4(__fsub_rn(cx, hw), __fsub_rn(cy, hh),
                                __fadd_rn(cx, hw), __fadd_rn(cy, hh));
        int bj = bc - 5;
        recG[(size_t)row * 2]     = bb;
        recG[(size_t)row * 2 + 1] = make_float4(__uint_as_float((unsigned)bj), 0.f, 0.f, 0.f);
    }
}

// Fused select + mask + finalize: 16 blocks x 1024 threads, one block per image.
// All intermediates (candidates, suppression masks) stay in LDS.
// hist/csum (phases 1-2) overlap the 32KB mask array (later phases) via union.
__global__ __launch_bounds__(NT) void k_fused(const float4* __restrict__ recG,
                                              const float* __restrict__ scoreArr,
                                              const float* __restrict__ logits,
                                              float* __restrict__ out) {
    __shared__ union {
        struct { unsigned hist[HBINS]; unsigned csum[257]; } h;
        unsigned long long maskS[CAP2][8];
    } u;
    __shared__ unsigned long long keys[CAP2];
    __shared__ float4 cbox_s[CAP2];
    __shared__ float4 raw_s[CAP2];
    __shared__ unsigned ccls_s[CAP2];
    __shared__ unsigned long long maskT_s[8][64];
    __shared__ unsigned long long keepm_s[8];
    __shared__ unsigned kidx[64];
    __shared__ unsigned rowsrc_s[MAXDET];
    __shared__ int flags[2];  // 0=cnt 1=thr
    __shared__ int s_kept;

    int b = blockIdx.x, tid = threadIdx.x;
    int lane = tid & 63;

    for (int k = tid; k < HBINS; k += NT) u.h.hist[k] = 0u;
    if (tid == 0) { flags[0] = 0; flags[1] = 0; }
    __syncthreads();

    // phase 1: register-cache scores (float4: NN/4 = 6300 exactly) + LDS hist.
    // scan order is irrelevant: hist is commutative, compaction set is
    // order-independent, and the bitonic sort canonicalizes ordering.
    const float4* sa4 = reinterpret_cast<const float4*>(scoreArr + (size_t)b * NN);
    f4u sreg[7];
#pragma unroll
    for (int t = 0; t < 7; ++t) {
        int n4 = tid + t * NT;
        f4u s4;
        if (n4 < NN / 4) {
            float4 v = sa4[n4];
            s4[0] = v.x; s4[1] = v.y; s4[2] = v.z; s4[3] = v.w;
        } else {
            s4[0] = s4[1] = s4[2] = s4[3] = -1.0f;
        }
        sreg[t] = s4;
#pragma unroll
        for (int e = 0; e < 4; ++e) {
            float s = s4[e];
            if (s > 0.0f) {
                unsigned key = (__float_as_uint(s) - 0x3E800000u) >> 13;
                if (key > HBINS - 1) key = HBINS - 1;
                atomicAdd(&u.h.hist[key], 1u);
            }
        }
    }
    __syncthreads();

    // phase 2: suffix scan -> threshold bin (verified logic, verbatim)
    if (tid < 256) {
        unsigned cs = 0;
#pragma unroll
        for (int t = 0; t < 8; ++t) cs += u.h.hist[tid * 8 + t];
        u.h.csum[tid] = cs;
    }
    __syncthreads();
    for (int off = 1; off < 256; off <<= 1) {
        unsigned v = 0, add = 0;
        if (tid < 256) {
            v = u.h.csum[tid];
            add = (tid + off < 256) ? u.h.csum[tid + off] : 0u;
        }
        __syncthreads();
        if (tid < 256) u.h.csum[tid] = v + add;
        __syncthreads();
    }
    if (tid < 256) {
        unsigned Sc = u.h.csum[tid];
        unsigned Sn = (tid < 255) ? u.h.csum[tid + 1] : 0u;
        if (Sc >= TGT && (tid == 255 || Sn < TGT)) {
            unsigned cum = Sn;
            int t = tid * 8;
            for (int k = tid * 8 + 7; k >= tid * 8; --k) {
                cum += u.h.hist[k];
                if (cum >= TGT) { t = k; break; }
            }
            flags[1] = t;
        }
    }
    __syncthreads();
    unsigned thr = (unsigned)flags[1];

    // phase 3: wave-aggregated compaction (1 atomic per wave per round)
#pragma unroll
    for (int t = 0; t < 7; ++t) {
        int n4 = tid + t * NT;
#pragma unroll
        for (int e = 0; e < 4; ++e) {
            float s = sreg[t][e];
            int n = n4 * 4 + e;
            bool win = false;
            if (s > 0.0f) {
                unsigned key = (__float_as_uint(s) - 0x3E800000u) >> 13;
                if (key > HBINS - 1) key = HBINS - 1;
                win = (key >= thr);
            }
            unsigned long long m = __ballot(win);
            if (m) {
                int lead = __ffsll((long long)m) - 1;
                int base = 0;
                if (lane == lead) base = atomicAdd(&flags[0], __popcll(m));
                base = __shfl(base, lead);
                if (win) {
                    int pos = base + __popcll(m & ((1ULL << lane) - 1ULL));
                    if (pos < CAP2)
                        keys[pos] = ((unsigned long long)__float_as_uint(s) << 32)
                                  | (unsigned long long)(0xFFFFFFFFu - (unsigned)n);
                }
            }
        }
    }
    __syncthreads();
    int c = min(flags[0], CAP2);
    for (int p = tid; p < CAP2; p += NT)
        if (p >= c) keys[p] = 0ULL;
    __syncthreads();

    // phase 4: bitonic sort 512 u64 desc == (score desc, idx asc).
    // Hybrid: waves 0..7 hold one element/lane in registers; passes with
    // j<=32 are barrier-free shfl_xor; only j in {64,128,256} (6 passes)
    // exchange through LDS. 14 barriers total vs 45 in the pure-LDS version.
    {
        unsigned long long key = 0ULL;
        if (tid < CAP2) key = keys[tid];
        for (int k = 2; k <= CAP2; k <<= 1) {
            for (int j = k >> 1; j > 0; j >>= 1) {
                unsigned long long pr;
                if (j >= 64) {
                    __syncthreads();              // prior reads done before overwrite
                    if (tid < CAP2) keys[tid] = key;
                    __syncthreads();
                    pr = (tid < CAP2) ? keys[tid ^ j] : 0ULL;
                } else {
                    pr = __shfl_xor(key, j);
                }
                if (tid < CAP2) {
                    // element at lower index of a pair in a descending (k) run
                    // takes the max; all other cases derived by symmetry.
                    bool takemax = (((tid & j) == 0) == ((tid & k) == 0));
                    bool gt = key > pr;
                    key = (takemax == gt) ? key : pr;
                }
            }
        }
        __syncthreads();
        if (tid < CAP2) keys[tid] = key;
        __syncthreads();
    }

    // phase 5: fetch precomputed record per sorted candidate (2 x dwordx4,
    // single 128B line) — replaces the 85-scalar-load row recompute.
    if (tid < CAP2) {
        int p = tid;
        if (p < c) {
            int n = (int)(0xFFFFFFFFu - (unsigned)keys[p]);
            size_t rb = ((size_t)b * NN + n) * 2;
            float4 bb = recG[rb];
            unsigned bj = __float_as_uint(recG[rb + 1].x);
            raw_s[p] = bb;
            float off = __fmul_rn((float)bj, 4096.0f);
            cbox_s[p] = make_float4(__fadd_rn(bb.x, off), __fadd_rn(bb.y, off),
                                    __fadd_rn(bb.z, off), __fadd_rn(bb.w, off));
            ccls_s[p] = bj;
        } else {
            raw_s[p]  = make_float4(0.f, 0.f, 0.f, 0.f);
            cbox_s[p] = make_float4(0.f, 0.f, 0.f, 0.f);
            ccls_s[p] = 0u;
        }
    }
    __syncthreads();

    // mask phase: word-w suppression bits for all rows (row-major), in LDS.
    // 4096 (i,w) words as 2048 complement pairs {(i0,w0),(511-i0,7-w0)}:
    // exactly one of a pair is above-diagonal (both only when w0==i-block),
    // so every wave does ~2 active wave-words -> SIMD-balanced (was 14/12/10/8).
    for (int h = tid; h < CAP2 * 4; h += NT) {
        int i0 = h & (CAP2 - 1);
        int w0 = h >> 9;                         // 0..3, wave-uniform
#pragma unroll
        for (int s = 0; s < 2; ++s) {
            int i = s ? (CAP2 - 1 - i0) : i0;
            int w = s ? (7 - w0) : w0;           // wave-uniform -> cbox_s[j] broadcast
            int jbase = w << 6;
            unsigned long long m = 0ULL;
            if (i < c && i < jbase + 63) {
                float4 ci = cbox_s[i];
                float a1 = __fmul_rn(__fsub_rn(ci.z, ci.x), __fsub_rn(ci.w, ci.y));
#pragma unroll 4
                for (int jj = 0; jj < 64; ++jj) {
                    int j = jbase + jj;
                    float4 cj = cbox_s[j];
                    float ltx = fmaxf(ci.x, cj.x), lty = fmaxf(ci.y, cj.y);
                    float rbx = fminf(ci.z, cj.z), rby = fminf(ci.w, cj.w);
                    float ww = fmaxf(__fsub_rn(rbx, ltx), 0.0f);
                    float hh = fmaxf(__fsub_rn(rby, lty), 0.0f);
                    float inter = __fmul_rn(ww, hh);
                    if (j > i && inter > 0.0f) {
                        float a2 = __fmul_rn(__fsub_rn(cj.z, cj.x), __fsub_rn(cj.w, cj.y));
                        float denom = __fadd_rn(__fsub_rn(__fadd_rn(a1, a2), inter), 1e-9f);
                        if (inter / denom > IOU_T) m |= (1ULL << jj);
                    }
                }
            }
            u.maskS[i][w] = m;
        }
    }
    // transposed diagonal: column l holds bits of earlier same-word suppressors.
    if (tid < 512) {
        int w = tid >> 6, l = tid & 63;
        int jbase = w << 6, p = jbase + l;
        unsigned long long m = 0ULL;
        if (p < c) {
            float4 cl = cbox_s[p];
            float a2 = __fmul_rn(__fsub_rn(cl.z, cl.x), __fsub_rn(cl.w, cl.y));
            for (int ii = 0; ii < 64; ++ii) {
                float4 ci = cbox_s[jbase + ii];
                float ltx = fmaxf(ci.x, cl.x), lty = fmaxf(ci.y, cl.y);
                float rbx = fminf(ci.z, cl.z), rby = fminf(ci.w, cl.w);
                float ww = fmaxf(__fsub_rn(rbx, ltx), 0.0f);
                float hh = fmaxf(__fsub_rn(rby, lty), 0.0f);
                float inter = __fmul_rn(ww, hh);
                if (ii < l && inter > 0.0f) {
                    float a1 = __fmul_rn(__fsub_rn(ci.z, ci.x), __fsub_rn(ci.w, ci.y));
                    float denom = __fadd_rn(__fsub_rn(__fadd_rn(a1, a2), inter), 1e-9f);
                    if (inter / denom > IOU_T) m |= (1ULL << ii);
                }
            }
        }
        maskT_s[w][l] = m;
    }
    __syncthreads();

    // fin phase: ballot-fixpoint greedy resolve (exact) + outputs.
    if (tid < 64) {
        unsigned long long remq = 0ULL;  // lane q<8 owns rem word q
        int kept = 0;
        for (int w = 0; w < 8; ++w) {
            int base = w << 6;
            unsigned long long tw = __shfl(remq, w);
            bool pre = ((tw >> lane) & 1ULL) != 0ULL;
            bool validl = (base + lane) < c;
            unsigned long long Cl = maskT_s[w][lane];
            unsigned long long initK = __ballot(validl && !pre);
            unsigned long long K = initK;
            // fixpoint: odd/even iterates sandwich the greedy set; exact on converge
            for (int it = 0; it < 64; ++it) {
                bool sup = (Cl & K & ((1ULL << lane) - 1ULL)) != 0ULL;
                unsigned long long K2 = initK & __ballot(!sup);
                if (K2 == K) break;
                K = K2;
            }
            // truncate to MAXDET total (reference scans exactly 300 picks)
            int limit = MAXDET - kept;
            int nk = __popcll(K);
            if (nk > limit) {
                if (limit <= 0) K = 0ULL;
                else {
                    int pref = __popcll(K & ((2ULL << lane) - 1ULL));  // bits 0..lane
                    bool el = ((K >> lane) & 1ULL) && (pref <= limit);
                    K = __ballot(el);
                }
            }
            kept += __popcll(K);
            if (lane == 0) keepm_s[w] = K;
            // cross-word rem update: 64 lanes fetch kept rows' words in parallel
            if (K != 0ULL && w < 7) {
                if ((K >> lane) & 1ULL) {
                    int r = __popcll(K & ((1ULL << lane) - 1ULL));
                    kidx[r] = (unsigned)lane;
                }
                __builtin_amdgcn_s_waitcnt(0);
                int nkk = __popcll(K);
                int q = lane & 7, slot = lane >> 3;
                unsigned long long acc = 0ULL;
                for (int t = slot; t < nkk; t += 8)
                    acc |= u.maskS[base + (int)kidx[t]][q];
                acc |= __shfl_xor(acc, 8);
                acc |= __shfl_xor(acc, 16);
                acc |= __shfl_xor(acc, 32);
                if (slot == 0) remq |= acc;
            }
        }
        if (lane == 0) s_kept = kept;
    }
    __syncthreads();
    int kept = s_kept;

    float* dets = out;
    float* lg   = out + (size_t)BB * MAXDET * 6;
    float* kpo  = lg  + (size_t)BB * MAXDET * NCLS;

    // rank-scatter kept rows directly to dets; record source indices
    for (int p = tid; p < CAP2; p += NT) {
        if (p < c) {
            int w = p >> 6, bitp = p & 63;
            unsigned long long kw = keepm_s[w];
            if ((kw >> bitp) & 1ULL) {
                int rank = __popcll(kw & ((1ULL << bitp) - 1ULL));
                for (int q = 0; q < w; ++q) rank += __popcll(keepm_s[q]);
                if (rank < MAXDET) {
                    float4 bb = raw_s[p];
                    unsigned long long key = keys[p];
                    float2* dr2 = reinterpret_cast<float2*>(
                        dets + ((size_t)b * MAXDET + rank) * 6);   // 24B stride, 8B aligned
                    dr2[0] = make_float2(bb.x, bb.y);
                    dr2[1] = make_float2(bb.z, bb.w);
                    dr2[2] = make_float2(__uint_as_float((unsigned)(key >> 32)),
                                         (float)ccls_s[p]);
                    rowsrc_s[rank] = 0xFFFFFFFFu - (unsigned)key;
                }
            }
        }
    }
    for (int i = tid; i < MAXDET; i += NT) {
        if (i >= kept) {
            float2* dr2 = reinterpret_cast<float2*>(
                dets + ((size_t)b * MAXDET + i) * 6);
            dr2[0] = make_float2(0.f, 0.f);
            dr2[1] = make_float2(0.f, 0.f);
            dr2[2] = make_float2(0.f, 0.f);
        }
        kpo[b * MAXDET + i] = (i < kept) ? 1.0f : 0.0f;
    }
    __syncthreads();
    // logits gather, float4-vectorized (rows are 320B, 16B-aligned both sides)
    {
        const int QC = NCLS / 4;  // 20
        for (int i4 = tid; i4 < MAXDET * QC; i4 += NT) {
            int t = i4 / QC, c4 = i4 - t * QC;
            float4 v = make_float4(0.f, 0.f, 0.f, 0.f);
            if (t < kept)
                v = *reinterpret_cast<const float4*>(
                        logits + ((size_t)b * NN + rowsrc_s[t]) * NCLS + c4 * 4);
            *reinterpret_cast<float4*>(
                lg + (size_t)b * MAXDET * NCLS + (size_t)t * NCLS + c4 * 4) = v;
        }
    }
}

extern "C" void kernel_launch(void* const* d_in, const int* in_sizes, int n_in,
                              void* d_out, int out_size, void* d_ws, size_t ws_size,
                              hipStream_t stream) {
    const float* pred   = (const float*)d_in[0];
    const float* logits = (const float*)d_in[1];
    float* out = (float*)d_out;
    char* ws = (char*)d_ws;

    float* scr   = (float*)ws;
    float4* recG = (float4*)(ws + OFF_REC);

    k_pre<<<6300, 256, 0, stream>>>(pred, scr, recG);           // 403200/64 exact
    k_fused<<<BB, NT, 0, stream>>>(recG, scr, logits, out);
}